// Round 4
// baseline (637.743 us; speedup 1.0000x reference)
//
#include <hip/hip_runtime.h>
#include <hip/hip_bf16.h>

typedef __bf16 bf16_t;
typedef __attribute__((ext_vector_type(8))) __bf16 bf16x8;
typedef __attribute__((ext_vector_type(4))) float f32x4;

#define BH 64
#define KP 512
#define NN 4096
#define DD 64
#define GSZ (BH * KP * DD)  // offset of gV in d_out

#define MFMA16(a, b, c) __builtin_amdgcn_mfma_f32_16x16x32_bf16((a), (b), (c), 0, 0, 0)

// Load 8 consecutive f32 and convert to a bf16x8 MFMA fragment.
__device__ __forceinline__ bf16x8 cvt8(const float* __restrict__ p) {
  const f32x4 lo = *(const f32x4*)p;
  const f32x4 hi = *(const f32x4*)(p + 4);
  bf16x8 r;
  r[0] = (bf16_t)lo[0]; r[1] = (bf16_t)lo[1]; r[2] = (bf16_t)lo[2]; r[3] = (bf16_t)lo[3];
  r[4] = (bf16_t)hi[0]; r[5] = (bf16_t)hi[1]; r[6] = (bf16_t)hi[2]; r[7] = (bf16_t)hi[3];
  return r;
}

// ---------------------------------------------------------------------------
// Pass 1: inv_colsum[bh][n] = 1 / sum_k exp(S[k,n]),  S = K . xk^T over d.
// Grid: (NN/64, BH) x 256 threads. Wave w handles 16 columns n0+w*16..+15,
// loops all 512 k rows.
// ---------------------------------------------------------------------------
__global__ __launch_bounds__(256) void hop_pass1(
    const float* __restrict__ Km, const float* __restrict__ xk,
    float* __restrict__ inv_colsum)
{
  const int tid  = threadIdx.x;
  const int wave = tid >> 6, lane = tid & 63;
  const int col  = lane & 15, quad = lane >> 4;
  const int bh = blockIdx.y;
  const int n0 = blockIdx.x * 64 + wave * 16;

  const float* xkb = xk + (size_t)bh * NN * DD;
  const float* Kb  = Km + (size_t)bh * KP * DD;

  // B frags: B[kk=d][n=col] = xk[n0+col][d], d = dh*32 + quad*8 + j
  const bf16x8 b0 = cvt8(xkb + (n0 + col) * DD + quad * 8);
  const bf16x8 b1 = cvt8(xkb + (n0 + col) * DD + 32 + quad * 8);

  float colacc = 0.f;
  for (int k0 = 0; k0 < KP; k0 += 16) {
    // A frags: A[m=col][kk=d] = K[k0+col][d]
    const bf16x8 a0 = cvt8(Kb + (k0 + col) * DD + quad * 8);
    const bf16x8 a1 = cvt8(Kb + (k0 + col) * DD + 32 + quad * 8);
    f32x4 c = {0.f, 0.f, 0.f, 0.f};
    c = MFMA16(a0, b0, c);
    c = MFMA16(a1, b1, c);
    // C layout: col = lane&15 (n), row = quad*4+r (k). Sum exp over our rows.
    colacc += __expf(c[0]) + __expf(c[1]) + __expf(c[2]) + __expf(c[3]);
  }
  // reduce across the 4 quads holding the same column
  colacc += __shfl_xor(colacc, 16, 64);
  colacc += __shfl_xor(colacc, 32, 64);
  if (lane < 16) inv_colsum[bh * NN + n0 + lane] = 1.0f / colacc;
}

// ---------------------------------------------------------------------------
// Pass 2: flash-style. Each workgroup: one bh, 64 k rows (wave -> 16 rows).
// Loop n in tiles of 32: S (4 MFMAs), w = exp(S)*inv_colsum, C-layout ->
// A-layout via per-wave LDS tile, PV matmuls (8 MFMAs) with B-frags from
// LDS-transposed xk/xv tiles. rowsum accumulated from w A-frag.
// Output: f32 (harness-verified read path).
// ---------------------------------------------------------------------------
#define PITCH 40  // bf16 elements per LDS row: 64B payload + 16B pad

__global__ __launch_bounds__(256) void hop_pass2(
    const float* __restrict__ Km, const float* __restrict__ Vm,
    const float* __restrict__ xk, const float* __restrict__ xv,
    const float* __restrict__ inv_colsum, float* __restrict__ out)
{
  __shared__ __align__(16) bf16_t xkT[DD * PITCH];      // [d][n] transposed tile
  __shared__ __align__(16) bf16_t xvT[DD * PITCH];
  __shared__ __align__(16) bf16_t wt[4][16 * PITCH];    // per-wave w tile [k_local][n]

  const int tid  = threadIdx.x;
  const int wave = tid >> 6, lane = tid & 63;
  const int col  = lane & 15, quad = lane >> 4;
  const int bh   = blockIdx.x >> 3;
  const int k0   = (blockIdx.x & 7) * 64 + wave * 16;

  const float* Kb  = Km + (size_t)bh * KP * DD;
  const float* Vb  = Vm + (size_t)bh * KP * DD;
  const float* xkb = xk + (size_t)bh * NN * DD;
  const float* xvb = xv + (size_t)bh * NN * DD;
  const float* inv = inv_colsum + bh * NN;

  // S A-frags: our 16 K rows, loaded once (A[m=col][kk=d])
  const bf16x8 ak0 = cvt8(Kb + (k0 + col) * DD + quad * 8);
  const bf16x8 ak1 = cvt8(Kb + (k0 + col) * DD + 32 + quad * 8);

  f32x4 accK[4], accV[4];
  #pragma unroll
  for (int i = 0; i < 4; i++) {
    accK[i] = (f32x4){0.f, 0.f, 0.f, 0.f};
    accV[i] = (f32x4){0.f, 0.f, 0.f, 0.f};
  }
  float rows_part = 0.f;

  // staging assignment: thread t loads xk/xv[n0+sn][sd..sd+7], scatters to [d][n]
  const int sn = tid >> 3;        // 0..31
  const int sd = (tid & 7) * 8;   // 0,8,..,56

  for (int n0 = 0; n0 < NN; n0 += 32) {
    // global loads first (no LDS dependency)
    const f32x4 gk0 = *(const f32x4*)(xkb + (n0 + sn) * DD + sd);
    const f32x4 gk1 = *(const f32x4*)(xkb + (n0 + sn) * DD + sd + 4);
    const f32x4 gv0 = *(const f32x4*)(xvb + (n0 + sn) * DD + sd);
    const f32x4 gv1 = *(const f32x4*)(xvb + (n0 + sn) * DD + sd + 4);
    // S B-frags: B[kk=d][n=col] = xk[n0(+16)+col][d]
    const bf16x8 b00 = cvt8(xkb + (n0 + col) * DD + quad * 8);
    const bf16x8 b01 = cvt8(xkb + (n0 + col) * DD + 32 + quad * 8);
    const bf16x8 b10 = cvt8(xkb + (n0 + 16 + col) * DD + quad * 8);
    const bf16x8 b11 = cvt8(xkb + (n0 + 16 + col) * DD + 32 + quad * 8);
    const float ic0 = inv[n0 + col];
    const float ic1 = inv[n0 + 16 + col];

    __syncthreads();  // previous iteration's LDS reads complete
    #pragma unroll
    for (int j = 0; j < 4; j++) {
      xkT[(sd + j) * PITCH + sn]     = (bf16_t)gk0[j];
      xkT[(sd + 4 + j) * PITCH + sn] = (bf16_t)gk1[j];
      xvT[(sd + j) * PITCH + sn]     = (bf16_t)gv0[j];
      xvT[(sd + 4 + j) * PITCH + sn] = (bf16_t)gv1[j];
    }

    f32x4 s0 = {0.f, 0.f, 0.f, 0.f}, s1 = {0.f, 0.f, 0.f, 0.f};
    s0 = MFMA16(ak0, b00, s0);
    s0 = MFMA16(ak1, b01, s0);
    s1 = MFMA16(ak0, b10, s1);
    s1 = MFMA16(ak1, b11, s1);

    // w = exp(S) * inv_colsum, C layout (row k_local = quad*4+r, col n = col)
    bf16_t* wrow = wt[wave];
    #pragma unroll
    for (int r = 0; r < 4; r++) {
      wrow[(quad * 4 + r) * PITCH + col]      = (bf16_t)(__expf(s0[r]) * ic0);
      wrow[(quad * 4 + r) * PITCH + 16 + col] = (bf16_t)(__expf(s1[r]) * ic1);
    }
    __syncthreads();  // staging + w writes visible

    // w as A-operand: A[m=col][kk=n=quad*8+j] -> one 16B LDS read
    const bf16x8 wa = *(const bf16x8*)(wt[wave] + col * PITCH + quad * 8);
    #pragma unroll
    for (int j = 0; j < 8; j++) rows_part += (float)wa[j];  // rowsum partial

    // PV: acc[k][d] += w . x,  B[kk=n][col2=d] from transposed LDS tile
    #pragma unroll
    for (int dt = 0; dt < 4; dt++) {
      const bf16x8 bk = *(const bf16x8*)(xkT + (dt * 16 + col) * PITCH + quad * 8);
      const bf16x8 bv = *(const bf16x8*)(xvT + (dt * 16 + col) * PITCH + quad * 8);
      accK[dt] = MFMA16(wa, bk, accK[dt]);
      accV[dt] = MFMA16(wa, bv, accV[dt]);
    }
  }

  // rowsum: reduce quads; lane l then holds rowsum[k0 + (l&15)]
  float rs = rows_part;
  rs += __shfl_xor(rs, 16, 64);
  rs += __shfl_xor(rs, 32, 64);
  float invrs[4];
  #pragma unroll
  for (int r = 0; r < 4; r++) invrs[r] = 1.0f / __shfl(rs, quad * 4 + r, 64);

  // epilogue: acc C layout row k_local = quad*4+r, col d = dt*16+col. f32 out.
  const size_t base = (size_t)bh * KP * DD;
  #pragma unroll
  for (int dt = 0; dt < 4; dt++) {
    #pragma unroll
    for (int r = 0; r < 4; r++) {
      const int k = k0 + quad * 4 + r;
      const int d = dt * 16 + col;
      const size_t idx = base + (size_t)k * DD + d;
      out[idx]       = accK[dt][r] * invrs[r] - Kb[k * DD + d];
      out[GSZ + idx] = accV[dt][r] * invrs[r] - Vb[k * DD + d];
    }
  }
}

extern "C" void kernel_launch(void* const* d_in, const int* in_sizes, int n_in,
                              void* d_out, int out_size, void* d_ws, size_t ws_size,
                              hipStream_t stream)
{
  (void)in_sizes; (void)n_in; (void)out_size; (void)ws_size;
  const float* Km = (const float*)d_in[0];
  const float* Vm = (const float*)d_in[1];
  const float* xk = (const float*)d_in[2];
  const float* xv = (const float*)d_in[3];
  float* inv_colsum = (float*)d_ws;  // BH*NN floats = 1 MB
  float* out = (float*)d_out;

  hop_pass1<<<dim3(NN / 64, BH), 256, 0, stream>>>(Km, xk, inv_colsum);
  hop_pass2<<<BH * (KP / 64), 256, 0, stream>>>(Km, Vm, xk, xv, inv_colsum, out);
}

// Round 5
// 331.206 us; speedup vs baseline: 1.9255x; 1.9255x over previous
//
#include <hip/hip_runtime.h>
#include <hip/hip_bf16.h>

typedef __bf16 bf16_t;
typedef __attribute__((ext_vector_type(8))) __bf16 bf16x8;
typedef __attribute__((ext_vector_type(4))) float f32x4;

#define BH 64
#define KP 512
#define NN 4096
#define DD 64
#define GSZ (BH * KP * DD)  // offset of gV in d_out

#define MFMA16(a, b, c) __builtin_amdgcn_mfma_f32_16x16x32_bf16((a), (b), (c), 0, 0, 0)

__device__ __forceinline__ bf16x8 cvt8v(const f32x4 lo, const f32x4 hi) {
  bf16x8 r;
  r[0] = (bf16_t)lo[0]; r[1] = (bf16_t)lo[1]; r[2] = (bf16_t)lo[2]; r[3] = (bf16_t)lo[3];
  r[4] = (bf16_t)hi[0]; r[5] = (bf16_t)hi[1]; r[6] = (bf16_t)hi[2]; r[7] = (bf16_t)hi[3];
  return r;
}
__device__ __forceinline__ bf16x8 cvt8(const float* __restrict__ p) {
  return cvt8v(*(const f32x4*)p, *(const f32x4*)(p + 4));
}

// ---------------------------------------------------------------------------
// Pass 1: inv_colsum[bh][n] = 1 / sum_k exp(K[k].xk[n]).
// Grid (NN/256, BH) x 256. Wave owns 64 columns (4 n-subtiles of 16); K is
// staged bf16 into LDS in 128-row chunks (read from global ONCE per WG,
// coalesced) and served as b128 A-frags. B-frags (xk rows) held in regs.
// ---------------------------------------------------------------------------
__global__ __launch_bounds__(256) void hop_pass1(
    const float* __restrict__ Km, const float* __restrict__ xk,
    float* __restrict__ inv_colsum)
{
  __shared__ __align__(16) bf16_t Ks[128 * 72];  // [k][d], pitch 72 elems

  const int tid  = threadIdx.x;
  const int wave = tid >> 6, lane = tid & 63;
  const int col  = lane & 15, quad = lane >> 4;
  const int bh = blockIdx.y;
  const int n0 = blockIdx.x * 256 + wave * 64;

  const float* Kb  = Km + (size_t)bh * KP * DD;
  const float* xkb = xk + (size_t)bh * NN * DD;

  // B frags: B[kk=d][n=col] = xk[n0+nsub*16+col][d]
  bf16x8 bf[4][2];
  #pragma unroll
  for (int nsub = 0; nsub < 4; nsub++) {
    const float* p = xkb + (size_t)(n0 + nsub * 16 + col) * DD + quad * 8;
    bf[nsub][0] = cvt8(p);
    bf[nsub][1] = cvt8(p + 32);
  }

  float colacc[4] = {0.f, 0.f, 0.f, 0.f};
  const int srow = tid >> 1, sdo = (tid & 1) * 32;  // staging: half row each

  for (int kc = 0; kc < KP; kc += 128) {
    __syncthreads();  // previous chunk's readers done
    const float* src = Kb + (size_t)(kc + srow) * DD + sdo;
    #pragma unroll
    for (int u = 0; u < 4; u++) {
      const f32x4 p0 = *(const f32x4*)(src + 8 * u);
      const f32x4 p1 = *(const f32x4*)(src + 8 * u + 4);
      *(bf16x8*)(Ks + srow * 72 + sdo + 8 * u) = cvt8v(p0, p1);
    }
    __syncthreads();
    #pragma unroll
    for (int ks = 0; ks < 8; ks++) {
      const bf16x8 a0 = *(const bf16x8*)(Ks + (ks * 16 + col) * 72 + quad * 8);
      const bf16x8 a1 = *(const bf16x8*)(Ks + (ks * 16 + col) * 72 + 32 + quad * 8);
      #pragma unroll
      for (int nsub = 0; nsub < 4; nsub++) {
        f32x4 c = {0.f, 0.f, 0.f, 0.f};
        c = MFMA16(a0, bf[nsub][0], c);
        c = MFMA16(a1, bf[nsub][1], c);
        colacc[nsub] += __expf(c[0]) + __expf(c[1]) + __expf(c[2]) + __expf(c[3]);
      }
    }
  }
  // reduce quads; lane (col,quad) publishes column n0 + quad*16 + col
  #pragma unroll
  for (int nsub = 0; nsub < 4; nsub++) {
    colacc[nsub] += __shfl_xor(colacc[nsub], 16, 64);
    colacc[nsub] += __shfl_xor(colacc[nsub], 32, 64);
  }
  float v = colacc[0];
  v = (quad == 1) ? colacc[1] : v;
  v = (quad == 2) ? colacc[2] : v;
  v = (quad == 3) ? colacc[3] : v;
  inv_colsum[bh * NN + n0 + quad * 16 + col] = 1.0f / v;
}

// ---------------------------------------------------------------------------
// Pass 2: flash-style, n-tile 64. LDS: natural xk tile (S B-frags, b128),
// XOR-swizzled transposed xk/xv tiles (PV B-frags, b128; scatter writes are
// 2-way-same-dword = conflict-free), per-wave w tile (pitch 72).
// xkT/xvT layout: elem(d,n) at d*64 + (((n>>3)^(d>>3))<<3) + (n&7).
// ---------------------------------------------------------------------------
#define NT 64
#define PW 72

__global__ __launch_bounds__(256) void hop_pass2(
    const float* __restrict__ Km, const float* __restrict__ Vm,
    const float* __restrict__ xk, const float* __restrict__ xv,
    const float* __restrict__ inv_colsum, float* __restrict__ out)
{
  __shared__ __align__(16) bf16_t xks[NT * PW];   // natural [n][d]
  __shared__ __align__(16) bf16_t xkT[DD * NT];   // swizzled [d][n]
  __shared__ __align__(16) bf16_t xvT[DD * NT];
  __shared__ __align__(16) bf16_t wt[4][16 * PW]; // per-wave w [k][n]

  const int tid  = threadIdx.x;
  const int wave = tid >> 6, lane = tid & 63;
  const int col  = lane & 15, quad = lane >> 4;
  const int bh   = blockIdx.x >> 3;
  const int k0   = (blockIdx.x & 7) * 64 + wave * 16;

  const float* Kb  = Km + (size_t)bh * KP * DD;
  const float* Vb  = Vm + (size_t)bh * KP * DD;
  const float* xkb = xk + (size_t)bh * NN * DD;
  const float* xvb = xv + (size_t)bh * NN * DD;
  const float* inv = inv_colsum + bh * NN;

  // S A-frags: our 16 K rows (A[m=col][kk=d]), loaded once
  const bf16x8 ak0 = cvt8(Kb + (size_t)(k0 + col) * DD + quad * 8);
  const bf16x8 ak1 = cvt8(Kb + (size_t)(k0 + col) * DD + 32 + quad * 8);

  f32x4 accK[4], accV[4];
  #pragma unroll
  for (int i = 0; i < 4; i++) {
    accK[i] = (f32x4){0.f, 0.f, 0.f, 0.f};
    accV[i] = (f32x4){0.f, 0.f, 0.f, 0.f};
  }
  float rows_part = 0.f;

  // staging: thread owns row sn, 16 consecutive d at sd
  const int sn = tid >> 2;        // 0..63
  const int sd = (tid & 3) * 16;  // 0,16,32,48
  const int shi = sn >> 3, slo = sn & 7;

  for (int n0 = 0; n0 < NN; n0 += NT) {
    // global loads (registers only — safe before barrier)
    f32x4 gk[4], gv[4];
    #pragma unroll
    for (int u = 0; u < 4; u++) {
      gk[u] = *(const f32x4*)(xkb + (size_t)(n0 + sn) * DD + sd + 4 * u);
      gv[u] = *(const f32x4*)(xvb + (size_t)(n0 + sn) * DD + sd + 4 * u);
    }
    float ic[4];
    #pragma unroll
    for (int nsub = 0; nsub < 4; nsub++) ic[nsub] = inv[n0 + nsub * 16 + col];

    __syncthreads();  // previous iteration's LDS readers done

    // natural xk tile: two b128 writes
    *(bf16x8*)(xks + sn * PW + sd)     = cvt8v(gk[0], gk[1]);
    *(bf16x8*)(xks + sn * PW + sd + 8) = cvt8v(gk[2], gk[3]);
    // swizzled transposed tiles: scalar writes, 2-way-same-dword (free)
    #pragma unroll
    for (int j = 0; j < 16; j++) {
      const int d   = sd + j;
      const int off = d * NT + (((shi) ^ (d >> 3)) << 3) + slo;
      xkT[off] = (bf16_t)gk[j >> 2][j & 3];
      xvT[off] = (bf16_t)gv[j >> 2][j & 3];
    }
    __syncthreads();  // staging visible

    // S: 16k x 64n via 8 MFMAs, B-frags b128 from natural tile
    f32x4 s[4];
    #pragma unroll
    for (int nsub = 0; nsub < 4; nsub++) {
      const bf16x8 b0 = *(const bf16x8*)(xks + (nsub * 16 + col) * PW + quad * 8);
      const bf16x8 b1 = *(const bf16x8*)(xks + (nsub * 16 + col) * PW + 32 + quad * 8);
      f32x4 c = {0.f, 0.f, 0.f, 0.f};
      c = MFMA16(ak0, b0, c);
      c = MFMA16(ak1, b1, c);
      s[nsub] = c;
    }
    // w = exp(S)*inv_colsum -> per-wave tile (C-layout scatter, ~2-way)
    bf16_t* wr = wt[wave];
    #pragma unroll
    for (int nsub = 0; nsub < 4; nsub++) {
      #pragma unroll
      for (int r = 0; r < 4; r++)
        wr[(quad * 4 + r) * PW + nsub * 16 + col] = (bf16_t)(__expf(s[nsub][r]) * ic[nsub]);
    }
    // same-wave LDS write->read: lgkmcnt ordering suffices (no barrier)
    const bf16x8 wa0 = *(const bf16x8*)(wr + col * PW + quad * 8);
    const bf16x8 wa1 = *(const bf16x8*)(wr + col * PW + 32 + quad * 8);
    #pragma unroll
    for (int j = 0; j < 8; j++) rows_part += (float)wa0[j] + (float)wa1[j];

    // PV: acc[k][d] += w . x, B-frags b128 from swizzled tiles
    #pragma unroll
    for (int dt = 0; dt < 4; dt++) {
      const int d = dt * 16 + col, dhi = d >> 3;
      const bf16x8 bk0 = *(const bf16x8*)(xkT + d * NT + ((quad ^ dhi) << 3));
      const bf16x8 bk1 = *(const bf16x8*)(xkT + d * NT + (((4 + quad) ^ dhi) << 3));
      const bf16x8 bv0 = *(const bf16x8*)(xvT + d * NT + ((quad ^ dhi) << 3));
      const bf16x8 bv1 = *(const bf16x8*)(xvT + d * NT + (((4 + quad) ^ dhi) << 3));
      accK[dt] = MFMA16(wa0, bk0, accK[dt]);
      accK[dt] = MFMA16(wa1, bk1, accK[dt]);
      accV[dt] = MFMA16(wa0, bv0, accV[dt]);
      accV[dt] = MFMA16(wa1, bv1, accV[dt]);
    }
  }

  // rowsum: reduce quads; invrs per C-row
  float rs = rows_part;
  rs += __shfl_xor(rs, 16, 64);
  rs += __shfl_xor(rs, 32, 64);
  float invrs[4];
  #pragma unroll
  for (int r = 0; r < 4; r++) invrs[r] = 1.0f / __shfl(rs, quad * 4 + r, 64);

  // epilogue: C layout row = quad*4+r, col d = dt*16+col. f32 out.
  const size_t base = (size_t)bh * KP * DD;
  #pragma unroll
  for (int dt = 0; dt < 4; dt++) {
    #pragma unroll
    for (int r = 0; r < 4; r++) {
      const int k = k0 + quad * 4 + r;
      const int d = dt * 16 + col;
      const size_t idx = base + (size_t)k * DD + d;
      out[idx]       = accK[dt][r] * invrs[r] - Kb[(size_t)k * DD + d];
      out[GSZ + idx] = accV[dt][r] * invrs[r] - Vb[(size_t)k * DD + d];
    }
  }
}

extern "C" void kernel_launch(void* const* d_in, const int* in_sizes, int n_in,
                              void* d_out, int out_size, void* d_ws, size_t ws_size,
                              hipStream_t stream)
{
  (void)in_sizes; (void)n_in; (void)out_size; (void)ws_size;
  const float* Km = (const float*)d_in[0];
  const float* Vm = (const float*)d_in[1];
  const float* xk = (const float*)d_in[2];
  const float* xv = (const float*)d_in[3];
  float* inv_colsum = (float*)d_ws;  // BH*NN floats = 1 MB
  float* out = (float*)d_out;

  hop_pass1<<<dim3(NN / 256, BH), 256, 0, stream>>>(Km, xk, inv_colsum);
  hop_pass2<<<BH * (KP / 64), 256, 0, stream>>>(Km, Vm, xk, xv, inv_colsum, out);
}